// Round 1
// baseline (199.395 us; speedup 1.0000x reference)
//
#include <hip/hip_runtime.h>
#include <stdint.h>

#define M_DIM 16384
#define N_DIM 2048
#define K_DIM 2048
#define BM 128
#define BN 128
#define BK 32

typedef __bf16 bf16_t;
typedef __bf16 bf16x8 __attribute__((ext_vector_type(8)));
typedef __bf16 bf16x4 __attribute__((ext_vector_type(4)));
typedef float f32x4 __attribute__((ext_vector_type(4)));

__device__ __forceinline__ void gload_lds16(const void* g, void* l) {
  __builtin_amdgcn_global_load_lds(
      (const __attribute__((address_space(1))) void*)g,
      (__attribute__((address_space(3))) void*)l, 16, 0, 0);
}

// float -> bf16 (RNE). SIGN applies sign() first (exact in bf16).
template <bool SIGN>
__global__ void cvt_kernel(const float* __restrict__ in, bf16_t* __restrict__ out) {
  long long i = ((long long)blockIdx.x * 256 + threadIdx.x) * 8;
  const float4* p = (const float4*)(in + i);
  float4 v0 = p[0];
  float4 v1 = p[1];
  float f[8] = {v0.x, v0.y, v0.z, v0.w, v1.x, v1.y, v1.z, v1.w};
  bf16x8 r;
#pragma unroll
  for (int j = 0; j < 8; ++j) {
    float v = f[j];
    if (SIGN) v = (v > 0.f) ? 1.f : ((v < 0.f) ? -1.f : 0.f);
    r[j] = (bf16_t)v;
  }
  *(bf16x8*)(out + i) = r;
}

// C[M,N] = alpha * A[M,K] * B[N,K]^T  (bf16 MFMA, f32 accumulate)
// FUSED=false: A,B are pre-converted bf16, staged via global_load_lds (width 16).
// FUSED=true : A,B are f32; reg-stage + convert on the fly (workspace-free fallback).
template <bool FUSED>
__global__ __launch_bounds__(256) void gemm_bt(const void* __restrict__ Ap,
                                               const void* __restrict__ Bp,
                                               const float* __restrict__ alpha_p,
                                               float* __restrict__ C) {
  __shared__ bf16_t As[BM * BK];
  __shared__ bf16_t Bs[BN * BK];

  const int tid = threadIdx.x;
  const int lane = tid & 63;
  const int wid = tid >> 6;
  const int wr = wid >> 1;  // 2x2 wave grid; each wave owns a 64x64 sub-tile
  const int wc = wid & 1;

  // XCD-aware bijective swizzle (grid = 2048, 2048 % 8 == 0)
  const int cpx = gridDim.x >> 3;
  const int bid = blockIdx.x;
  const int swz = (bid & 7) * cpx + (bid >> 3);
  const int NB = N_DIM / BN;  // 16
  const int bm = swz / NB;
  const int bn = swz % NB;

  f32x4 acc[4][4];
#pragma unroll
  for (int m = 0; m < 4; ++m)
#pragma unroll
    for (int n = 0; n < 4; ++n) acc[m][n] = (f32x4){0.f, 0.f, 0.f, 0.f};

  const int r0 = lane & 15;
  const int ko = (lane >> 4) * 8;

  for (int kk = 0; kk < K_DIM; kk += BK) {
    if constexpr (!FUSED) {
      const bf16_t* A = (const bf16_t*)Ap + (size_t)bm * BM * K_DIM + kk;
      const bf16_t* B = (const bf16_t*)Bp + (size_t)bn * BN * K_DIM + kk;
#pragma unroll
      for (int q = 0; q < 2; ++q) {
        int e = q * 256 + tid;      // 512 chunks of 8 bf16 (16B)
        int row = e >> 2;           // 4 chunks per BK=32 row
        int kc = (e & 3) << 3;
        gload_lds16(A + (size_t)row * K_DIM + kc,
                    &As[(q * 256 + (tid & 192)) * 8]);  // wave-uniform LDS base
      }
#pragma unroll
      for (int q = 0; q < 2; ++q) {
        int e = q * 256 + tid;
        int row = e >> 2;
        int kc = (e & 3) << 3;
        gload_lds16(B + (size_t)row * K_DIM + kc,
                    &Bs[(q * 256 + (tid & 192)) * 8]);
      }
    } else {
      const float* A = (const float*)Ap + (size_t)bm * BM * K_DIM + kk;
      const float* B = (const float*)Bp + (size_t)bn * BN * K_DIM + kk;
#pragma unroll
      for (int q = 0; q < 4; ++q) {
        int e = q * 256 + tid;      // 1024 chunks of 4 f32 (16B)
        int row = e >> 3;           // 8 chunks per BK=32 row
        int kc = (e & 7) << 2;
        float4 v = *(const float4*)(A + (size_t)row * K_DIM + kc);
        bf16x4 t;
        t[0] = (bf16_t)v.x; t[1] = (bf16_t)v.y;
        t[2] = (bf16_t)v.z; t[3] = (bf16_t)v.w;
        *(bf16x4*)&As[e * 4] = t;
      }
#pragma unroll
      for (int q = 0; q < 4; ++q) {
        int e = q * 256 + tid;
        int row = e >> 3;
        int kc = (e & 7) << 2;
        float4 v = *(const float4*)(B + (size_t)row * K_DIM + kc);
        float s[4] = {v.x, v.y, v.z, v.w};
        bf16x4 t;
#pragma unroll
        for (int j = 0; j < 4; ++j) {
          float w = s[j];
          t[j] = (bf16_t)((w > 0.f) ? 1.f : ((w < 0.f) ? -1.f : 0.f));
        }
        *(bf16x4*)&Bs[e * 4] = t;
      }
    }
    __syncthreads();

    bf16x8 a[4], b[4];
#pragma unroll
    for (int m = 0; m < 4; ++m)
      a[m] = *(const bf16x8*)&As[(wr * 64 + m * 16 + r0) * BK + ko];
#pragma unroll
    for (int n = 0; n < 4; ++n)
      b[n] = *(const bf16x8*)&Bs[(wc * 64 + n * 16 + r0) * BK + ko];
#pragma unroll
    for (int m = 0; m < 4; ++m)
#pragma unroll
      for (int n = 0; n < 4; ++n)
        acc[m][n] = __builtin_amdgcn_mfma_f32_16x16x32_bf16(a[m], b[n], acc[m][n], 0, 0, 0);
    __syncthreads();
  }

  // Epilogue: C/D layout col=lane&15, row=(lane>>4)*4+reg (m89/m91-verified)
  const float alpha = alpha_p[0];
  const int rowb = bm * BM + wr * 64 + (lane >> 4) * 4;
  const int colb = bn * BN + wc * 64 + r0;
#pragma unroll
  for (int m = 0; m < 4; ++m)
#pragma unroll
    for (int n = 0; n < 4; ++n)
#pragma unroll
      for (int r = 0; r < 4; ++r) {
        int row = rowb + m * 16 + r;
        int col = colb + n * 16;
        C[(size_t)row * N_DIM + col] = alpha * acc[m][n][r];
      }
}

extern "C" void kernel_launch(void* const* d_in, const int* in_sizes, int n_in,
                              void* d_out, int out_size, void* d_ws, size_t ws_size,
                              hipStream_t stream) {
  const float* x = (const float*)d_in[0];
  const float* w = (const float*)d_in[1];
  const float* alpha = (const float*)d_in[2];
  float* out = (float*)d_out;

  const size_t nx = (size_t)M_DIM * K_DIM;
  const size_t nw = (size_t)N_DIM * K_DIM;
  const size_t need = (nx + nw) * sizeof(bf16_t);
  const int nblocks = (M_DIM / BM) * (N_DIM / BN);  // 2048

  if (ws_size >= need) {
    bf16_t* xb = (bf16_t*)d_ws;
    bf16_t* wb = xb + nx;
    cvt_kernel<false><<<(int)(nx / 2048), 256, 0, stream>>>(x, xb);
    cvt_kernel<true><<<(int)(nw / 2048), 256, 0, stream>>>(w, wb);
    gemm_bt<false><<<nblocks, 256, 0, stream>>>(xb, wb, alpha, out);
  } else {
    gemm_bt<true><<<nblocks, 256, 0, stream>>>(x, w, alpha, out);
  }
}

// Round 2
// 171.672 us; speedup vs baseline: 1.1615x; 1.1615x over previous
//
#include <hip/hip_runtime.h>
#include <stdint.h>

#define M_DIM 16384
#define N_DIM 2048
#define K_DIM 2048

typedef __bf16 bf16_t;
typedef __bf16 bf16x8 __attribute__((ext_vector_type(8)));
typedef __bf16 bf16x4 __attribute__((ext_vector_type(4)));
typedef float f32x4 __attribute__((ext_vector_type(4)));

__device__ __forceinline__ void gload_lds16(const void* g, void* l) {
  __builtin_amdgcn_global_load_lds(
      (const __attribute__((address_space(1))) void*)g,
      (__attribute__((address_space(3))) void*)l, 16, 0, 0);
}

// float -> bf16 (RNE). SIGN applies sign() first (exact in bf16).
template <bool SIGN>
__global__ void cvt_kernel(const float* __restrict__ in, bf16_t* __restrict__ out) {
  long long i = ((long long)blockIdx.x * 256 + threadIdx.x) * 8;
  const float4* p = (const float4*)(in + i);
  float4 v0 = p[0];
  float4 v1 = p[1];
  float f[8] = {v0.x, v0.y, v0.z, v0.w, v1.x, v1.y, v1.z, v1.w};
  bf16x8 r;
#pragma unroll
  for (int j = 0; j < 8; ++j) {
    float v = f[j];
    if (SIGN) v = (v > 0.f) ? 1.f : ((v < 0.f) ? -1.f : 0.f);
    r[j] = (bf16_t)v;
  }
  *(bf16x8*)(out + i) = r;
}

// ============================================================================
// 256x256 tile, BK=32, 8 waves (2m x 4n), 4-slot LDS ring, 2 phases per K-tile.
// Pipeline: while computing K-tile t (slot t&3), stage tile t+3 (slot (t-1)&3,
// fully consumed at tile t-1). vmcnt(8) once per tile (= tiles t+2,t+3 allowed
// in flight) placed immediately before a barrier -> collective landing
// guarantee for tile t+1. LDS bank swizzle: phys = log ^ (((row>>1)&3)<<4)
// applied to pre-swizzled global source (linear gload_lds dest) and ds_reads.
// ============================================================================
__global__ __launch_bounds__(512, 2) void gemm8(const bf16_t* __restrict__ A,
                                                const bf16_t* __restrict__ B,
                                                const float* __restrict__ alpha_p,
                                                float* __restrict__ C) {
  extern __shared__ char smem[];
  bf16_t* As = (bf16_t*)smem;              // 4 slots x 256x32 bf16 = 64 KiB
  bf16_t* Bs = (bf16_t*)(smem + 65536);    // 4 slots x 256x32 bf16 = 64 KiB

  const int tid = threadIdx.x;
  const int lane = tid & 63;
  const int wid = tid >> 6;
  const int wm = wid >> 2;   // 0..1 -> rows wm*128..+127
  const int wn = wid & 3;    // 0..3 -> cols wn*64..+63

  // XCD-aware bijective swizzle (512 blocks, 512 % 8 == 0)
  const int bid = blockIdx.x;
  const int swz = (bid & 7) * 64 + (bid >> 3);
  const int bm = swz >> 3;   // 0..63
  const int bn = swz & 7;    // 0..7

  const int r0 = lane & 15;
  const int c2 = (lane >> 4) << 4;  // logical byte col within 64B row

  // Stage one 256x32 bf16 tile (16 KiB): 2 gload_lds16 per thread.
  // LDS dest is linear (wave-uniform base + lane*16); source pre-swizzled.
  auto stage = [&](const bf16_t* __restrict__ G, int grow0, int kk, bf16_t* slot) {
#pragma unroll
    for (int q = 0; q < 2; ++q) {
      int P = q * 8192 + tid * 16;                       // phys byte in slot
      int row = P >> 6;                                  // 0..255
      int lcol = (P & 63) ^ (((row >> 1) & 3) << 4);     // logical byte-in-row
      gload_lds16(G + (size_t)(grow0 + row) * K_DIM + kk + (lcol >> 1),
                  slot + ((q * 8192 + wid * 1024) >> 1));  // wave-uniform
    }
  };
  // Swizzled ds_read of one 16B MFMA fragment.
  auto frag = [&](const bf16_t* slot, int row) -> bf16x8 {
    int pb = (row << 6) + (c2 ^ (((row >> 1) & 3) << 4));
    return *(const bf16x8*)((const char*)slot + pb);
  };

  f32x4 acc[8][4];
#pragma unroll
  for (int m = 0; m < 8; ++m)
#pragma unroll
    for (int n = 0; n < 4; ++n) acc[m][n] = (f32x4){0.f, 0.f, 0.f, 0.f};

  // Prologue: stage tiles 0,1,2 (12 loads/wave); wait for tile 0 (8 left).
#pragma unroll
  for (int tt = 0; tt < 3; ++tt) {
    stage(A, bm * 256, tt * 32, As + tt * 8192);
    stage(B, bn * 256, tt * 32, Bs + tt * 8192);
  }
  asm volatile("s_waitcnt vmcnt(8)" ::: "memory");
  __builtin_amdgcn_s_barrier();

#pragma unroll 1
  for (int t = 0; t < 64; ++t) {
    const bf16_t* Aslot = As + (t & 3) * 8192;
    const bf16_t* Bslot = Bs + (t & 3) * 8192;

    // ---- Phase A: frags m0-3 + all b; stage A(t+3); MFMA m0-3 x n0-3 ----
    bf16x8 a[4], b[4];
#pragma unroll
    for (int m = 0; m < 4; ++m) a[m] = frag(Aslot, wm * 128 + m * 16 + r0);
#pragma unroll
    for (int n = 0; n < 4; ++n) b[n] = frag(Bslot, wn * 64 + n * 16 + r0);
    if (t < 61) stage(A, bm * 256, (t + 3) * 32, As + ((t + 3) & 3) * 8192);
    __builtin_amdgcn_s_barrier();
    asm volatile("s_waitcnt lgkmcnt(0)" ::: "memory");
    __builtin_amdgcn_s_setprio(1);
#pragma unroll
    for (int m = 0; m < 4; ++m)
#pragma unroll
      for (int n = 0; n < 4; ++n)
        acc[m][n] = __builtin_amdgcn_mfma_f32_16x16x32_bf16(a[m], b[n], acc[m][n], 0, 0, 0);
    __builtin_amdgcn_s_setprio(0);
    __builtin_amdgcn_s_barrier();

    // ---- Phase B: frags m4-7 (b reused); stage B(t+3); vmcnt; MFMA ----
    bf16x8 a2[4];
#pragma unroll
    for (int m = 0; m < 4; ++m) a2[m] = frag(Aslot, wm * 128 + 64 + m * 16 + r0);
    if (t < 61) stage(B, bn * 256, (t + 3) * 32, Bs + ((t + 3) & 3) * 8192);
    if (t < 61) {
      asm volatile("s_waitcnt vmcnt(8)" ::: "memory");   // tiles t+2,t+3 in flight
    } else if (t == 61) {
      asm volatile("s_waitcnt vmcnt(4)" ::: "memory");   // tile 63 in flight
    } else {
      asm volatile("s_waitcnt vmcnt(0)" ::: "memory");
    }
    __builtin_amdgcn_s_barrier();
    asm volatile("s_waitcnt lgkmcnt(0)" ::: "memory");
    __builtin_amdgcn_s_setprio(1);
#pragma unroll
    for (int m = 0; m < 4; ++m)
#pragma unroll
      for (int n = 0; n < 4; ++n)
        acc[4 + m][n] = __builtin_amdgcn_mfma_f32_16x16x32_bf16(a2[m], b[n], acc[4 + m][n], 0, 0, 0);
    __builtin_amdgcn_s_setprio(0);
    __builtin_amdgcn_s_barrier();
  }

  // Epilogue: C/D layout col=lane&15, row=(lane>>4)*4+reg (verified round 1).
  const float alpha = alpha_p[0];
  const int rbase = bm * 256 + wm * 128 + ((lane >> 4) << 2);
  const int cbase = bn * 256 + wn * 64 + r0;
#pragma unroll
  for (int m = 0; m < 8; ++m)
#pragma unroll
    for (int n = 0; n < 4; ++n)
#pragma unroll
      for (int r = 0; r < 4; ++r)
        C[(size_t)(rbase + m * 16 + r) * N_DIM + cbase + n * 16] = alpha * acc[m][n][r];
}

// ---- Workspace-free fallback (round-1 verified structure, f32 reg-staged) ----
__global__ __launch_bounds__(256) void gemm_fallback(const float* __restrict__ Ap,
                                                     const float* __restrict__ Bp,
                                                     const float* __restrict__ alpha_p,
                                                     float* __restrict__ C) {
  __shared__ bf16_t Asf[128 * 32];
  __shared__ bf16_t Bsf[128 * 32];
  const int tid = threadIdx.x;
  const int lane = tid & 63;
  const int wid = tid >> 6;
  const int wr = wid >> 1;
  const int wc = wid & 1;
  const int cpx = gridDim.x >> 3;
  const int bid = blockIdx.x;
  const int swz = (bid & 7) * cpx + (bid >> 3);
  const int NB = N_DIM / 128;
  const int bm = swz / NB;
  const int bn = swz % NB;
  f32x4 acc[4][4];
#pragma unroll
  for (int m = 0; m < 4; ++m)
#pragma unroll
    for (int n = 0; n < 4; ++n) acc[m][n] = (f32x4){0.f, 0.f, 0.f, 0.f};
  const int r0 = lane & 15;
  const int ko = (lane >> 4) * 8;
  for (int kk = 0; kk < K_DIM; kk += 32) {
    const float* Af = Ap + (size_t)bm * 128 * K_DIM + kk;
    const float* Bf = Bp + (size_t)bn * 128 * K_DIM + kk;
#pragma unroll
    for (int q = 0; q < 4; ++q) {
      int e = q * 256 + tid;
      int row = e >> 3;
      int kc = (e & 7) << 2;
      float4 v = *(const float4*)(Af + (size_t)row * K_DIM + kc);
      bf16x4 tv;
      tv[0] = (bf16_t)v.x; tv[1] = (bf16_t)v.y; tv[2] = (bf16_t)v.z; tv[3] = (bf16_t)v.w;
      *(bf16x4*)&Asf[e * 4] = tv;
    }
#pragma unroll
    for (int q = 0; q < 4; ++q) {
      int e = q * 256 + tid;
      int row = e >> 3;
      int kc = (e & 7) << 2;
      float4 v = *(const float4*)(Bf + (size_t)row * K_DIM + kc);
      float s[4] = {v.x, v.y, v.z, v.w};
      bf16x4 tv;
#pragma unroll
      for (int j = 0; j < 4; ++j)
        tv[j] = (bf16_t)((s[j] > 0.f) ? 1.f : ((s[j] < 0.f) ? -1.f : 0.f));
      *(bf16x4*)&Bsf[e * 4] = tv;
    }
    __syncthreads();
    bf16x8 a[4], b[4];
#pragma unroll
    for (int m = 0; m < 4; ++m) a[m] = *(const bf16x8*)&Asf[(wr * 64 + m * 16 + r0) * 32 + ko];
#pragma unroll
    for (int n = 0; n < 4; ++n) b[n] = *(const bf16x8*)&Bsf[(wc * 64 + n * 16 + r0) * 32 + ko];
#pragma unroll
    for (int m = 0; m < 4; ++m)
#pragma unroll
      for (int n = 0; n < 4; ++n)
        acc[m][n] = __builtin_amdgcn_mfma_f32_16x16x32_bf16(a[m], b[n], acc[m][n], 0, 0, 0);
    __syncthreads();
  }
  const float alpha = alpha_p[0];
  const int rowb = bm * 128 + wr * 64 + (lane >> 4) * 4;
  const int colb = bn * 128 + wc * 64 + r0;
#pragma unroll
  for (int m = 0; m < 4; ++m)
#pragma unroll
    for (int n = 0; n < 4; ++n)
#pragma unroll
      for (int r = 0; r < 4; ++r)
        C[(size_t)(rowb + m * 16 + r) * N_DIM + colb + n * 16] = alpha * acc[m][n][r];
}

extern "C" void kernel_launch(void* const* d_in, const int* in_sizes, int n_in,
                              void* d_out, int out_size, void* d_ws, size_t ws_size,
                              hipStream_t stream) {
  const float* x = (const float*)d_in[0];
  const float* w = (const float*)d_in[1];
  const float* alpha = (const float*)d_in[2];
  float* out = (float*)d_out;

  const size_t nx = (size_t)M_DIM * K_DIM;
  const size_t nw = (size_t)N_DIM * K_DIM;
  const size_t need = (nx + nw) * sizeof(bf16_t);

  if (ws_size >= need) {
    bf16_t* xb = (bf16_t*)d_ws;
    bf16_t* wb = xb + nx;
    cvt_kernel<false><<<(int)(nx / 2048), 256, 0, stream>>>(x, xb);
    cvt_kernel<true><<<(int)(nw / 2048), 256, 0, stream>>>(w, wb);
    (void)hipFuncSetAttribute((const void*)gemm8,
                              hipFuncAttributeMaxDynamicSharedMemorySize, 131072);
    gemm8<<<512, 512, 131072, stream>>>(xb, wb, alpha, out);
  } else {
    gemm_fallback<<<(M_DIM / 128) * (N_DIM / 128), 256, 0, stream>>>(x, w, alpha, out);
  }
}